// Round 1
// baseline (415.234 us; speedup 1.0000x reference)
//
#include <hip/hip_runtime.h>

#define MM    12
#define TSOL  64
#define NXX   256
#define NYY   256
#define NTT   50
#define NOUTT 256
#define ROWS  4

// Per-(m,k) interpolation table, produced by setup_kernel each call.
__device__ int   g_iy[MM * NOUTT];
__device__ float g_w0[MM * NOUTT];
__device__ float g_w1[MM * NOUTT];

// grid: MM blocks x 256 threads. Block m computes table row m.
// Weight math is tiny and recomputed redundantly per block (parallel, ~us).
__global__ __launch_bounds__(256) void ai_setup_kernel(
    const float* __restrict__ params,
    const float* __restrict__ Wq, const float* __restrict__ bq,
    const float* __restrict__ Wk, const float* __restrict__ bk)
{
    const int k = threadIdx.x;
    const int m = blockIdx.x;

    __shared__ float s_attn[MM][4];
    __shared__ float s_sw[MM];
    __shared__ float s_wm;
    __shared__ float s_ys[NYY];

    if (k < MM) {
        float ly = params[k * 3 + 0];
        float p0 = (ly - 30.0f) / 90.0f;
        float p1 = params[k * 3 + 1] / 0.0029f;
        float p2 = params[k * 3 + 2] / 0.0018f;
        const float t0 = 0.5f;                 // (75-30)/90 exact
        const float t1 = 0.001f / 0.0029f;
        const float t2 = 0.0001f / 0.0018f;
        for (int h = 0; h < 4; ++h) {
            float acc = 0.0f;
            for (int d = 0; d < 8; ++d) {
                int o = h * 8 + d;
                float q  = t0 * Wq[o * 3 + 0] + t1 * Wq[o * 3 + 1] + t2 * Wq[o * 3 + 2] + bq[o];
                float kv = p0 * Wk[o * 3 + 0] + p1 * Wk[o * 3 + 1] + p2 * Wk[o * 3 + 2] + bk[o];
                acc += kv * q;
            }
            s_attn[k][h] = acc * 0.35355339059327373f;  // 1/sqrt(8)
        }
        float d0 = (p0 - t0) / 0.25f;
        float d1 = (p1 - t1) / 0.25f;
        float d2 = (p2 - t2) / 0.25f;
        s_sw[k] = expf(-(d0 * d0 + d1 * d1 + d2 * d2) * 0.5f);
    }
    __syncthreads();

    if (k == 0) {
        float aw[MM];
        for (int j = 0; j < MM; ++j) aw[j] = 0.0f;
        for (int h = 0; h < 4; ++h) {               // softmax over m, per head
            float mx = s_attn[0][h];
            for (int j = 1; j < MM; ++j) mx = fmaxf(mx, s_attn[j][h]);
            float e[MM]; float sum = 0.0f;
            for (int j = 0; j < MM; ++j) { e[j] = expf(s_attn[j][h] - mx); sum += e[j]; }
            for (int j = 0; j < MM; ++j) aw[j] += e[j] / sum;
        }
        float swsum = 0.0f;
        for (int j = 0; j < MM; ++j) swsum += s_sw[j];
        float wj[MM]; float wsum = 0.0f;
        for (int j = 0; j < MM; ++j) {
            wj[j] = (aw[j] * 0.25f) * (s_sw[j] / swsum);
            wsum += wj[j];
        }
        s_wm = wj[m] / wsum;
    }

    // ys row for this m — EXACT fp32 op sequence of the reference:
    // ys[j] = fl( fl(l01[j]*ly) * fl(75/ly) ),  l01[j] = fl(j * fl(1/255))
    {
        float ly  = params[m * 3 + 0];
        float inv = 75.0f / ly;                    // IEEE divide (no fast-math)
        float l01 = (float)k * (1.0f / 255.0f);
        s_ys[k] = (l01 * ly) * inv;
    }
    __syncthreads();

    float w  = s_wm;
    float yq = (float)k * (75.0f / 255.0f);        // rounds to exactly 75.0 at k=255
    // upper_bound: largest j with ys[j] <= yq  (== searchsorted 'right' - 1)
    int l = 0, r = NYY;
    while (l < r) { int mid = (l + r) >> 1; if (s_ys[mid] <= yq) l = mid + 1; else r = mid; }
    int iy = l - 1;
    iy = iy < 0 ? 0 : (iy > NYY - 2 ? NYY - 2 : iy);
    float ty  = (yq - s_ys[iy]) / (s_ys[iy + 1] - s_ys[iy]);
    bool  inb = (yq >= s_ys[0]) && (yq <= s_ys[NYY - 1]);   // the k=255 knife edge
    g_iy[m * NOUTT + k] = iy;
    g_w0[m * NOUTT + k] = inb ? w * (1.0f - ty) : 0.0f;
    g_w1[m * NOUTT + k] = inb ? w * ty : 0.0f;
}

// grid: (NOUTT/ROWS, NTT), block 256. Thread k = output y index.
// x-interp is identity, so each output row (t,i,k=*) is a weighted y-lerp of
// 12 source rows c[ch][m][tsrc][i][*] — near-coalesced gathers (iy ~ k).
__global__ __launch_bounds__(256) void ai_resample_kernel(
    const float* __restrict__ c1, const float* __restrict__ c2,
    float* __restrict__ out)
{
    const int k  = threadIdx.x;
    const int t  = blockIdx.y;
    const int i0 = blockIdx.x * ROWS;
    int tsrc = (t * TSOL) / (NTT - 1);             // floor(t*64/49), fp-robust
    if (tsrc > TSOL - 1) tsrc = TSOL - 1;

    int   iy[MM];
    float w0[MM], w1[MM];
#pragma unroll
    for (int m = 0; m < MM; ++m) {
        iy[m] = g_iy[m * NOUTT + k];
        w0[m] = g_w0[m * NOUTT + k];
        w1[m] = g_w1[m * NOUTT + k];
    }

    for (int r = 0; r < ROWS; ++r) {
        int i = i0 + r;
        size_t rowbase = ((size_t)tsrc * NXX + (size_t)i) * NYY;
        float acc1 = 0.0f, acc2 = 0.0f;
#pragma unroll
        for (int m = 0; m < MM; ++m) {
            size_t off = (size_t)m * (TSOL * NXX * NYY) + rowbase + (size_t)iy[m];
            float a0 = c1[off], a1 = c1[off + 1];
            float b0 = c2[off], b1 = c2[off + 1];
            acc1 += w0[m] * a0 + w1[m] * a1;
            acc2 += w0[m] * b0 + w1[m] * b1;
        }
        if (k == 0)         acc1 = 0.001f;         // c1[:, :, 0]  = C_CU_TARGET
        if (k == NOUTT - 1) acc2 = 0.0001f;        // c2[:, :, -1] = C_NI_TARGET
        out[((size_t)t * NOUTT + (size_t)i) * NOUTT + (size_t)k] = acc1;
        out[((size_t)(NTT + t) * NOUTT + (size_t)i) * NOUTT + (size_t)k] = acc2;
    }
}

extern "C" void kernel_launch(void* const* d_in, const int* in_sizes, int n_in,
                              void* d_out, int out_size, void* d_ws, size_t ws_size,
                              hipStream_t stream) {
    const float* params = (const float*)d_in[0];
    const float* c1     = (const float*)d_in[1];
    const float* c2     = (const float*)d_in[2];
    const float* Wq     = (const float*)d_in[3];
    const float* bq     = (const float*)d_in[4];
    const float* Wk     = (const float*)d_in[5];
    const float* bk     = (const float*)d_in[6];
    float* out = (float*)d_out;

    ai_setup_kernel<<<dim3(MM), dim3(256), 0, stream>>>(params, Wq, bq, Wk, bk);
    ai_resample_kernel<<<dim3(NOUTT / ROWS, NTT), dim3(256), 0, stream>>>(c1, c2, out);
}

// Round 2
// 405.384 us; speedup vs baseline: 1.0243x; 1.0243x over previous
//
#include <hip/hip_runtime.h>

#define MM    12
#define TSOL  64
#define NXX   256
#define NYY   256
#define NTT   50
#define NOUTT 256
#define IPB   2     // output rows (i) per block; LDS = IPB*24 KB

// Per-(m,k) interpolation table, produced by setup_kernel each call.
__device__ int   g_iy[MM * NOUTT];
__device__ float g_w0[MM * NOUTT];
__device__ float g_w1[MM * NOUTT];

// grid: MM blocks x 256 threads. Block m computes table row m.
__global__ __launch_bounds__(256) void ai_setup_kernel(
    const float* __restrict__ params,
    const float* __restrict__ Wq, const float* __restrict__ bq,
    const float* __restrict__ Wk, const float* __restrict__ bk)
{
    const int k = threadIdx.x;
    const int m = blockIdx.x;

    __shared__ float s_attn[MM][4];
    __shared__ float s_sw[MM];
    __shared__ float s_wm;
    __shared__ float s_ys[NYY];

    if (k < MM) {
        float ly = params[k * 3 + 0];
        float p0 = (ly - 30.0f) / 90.0f;
        float p1 = params[k * 3 + 1] / 0.0029f;
        float p2 = params[k * 3 + 2] / 0.0018f;
        const float t0 = 0.5f;                 // (75-30)/90 exact
        const float t1 = 0.001f / 0.0029f;
        const float t2 = 0.0001f / 0.0018f;
        for (int h = 0; h < 4; ++h) {
            float acc = 0.0f;
            for (int d = 0; d < 8; ++d) {
                int o = h * 8 + d;
                float q  = t0 * Wq[o * 3 + 0] + t1 * Wq[o * 3 + 1] + t2 * Wq[o * 3 + 2] + bq[o];
                float kv = p0 * Wk[o * 3 + 0] + p1 * Wk[o * 3 + 1] + p2 * Wk[o * 3 + 2] + bk[o];
                acc += kv * q;
            }
            s_attn[k][h] = acc * 0.35355339059327373f;  // 1/sqrt(8)
        }
        float d0 = (p0 - t0) / 0.25f;
        float d1 = (p1 - t1) / 0.25f;
        float d2 = (p2 - t2) / 0.25f;
        s_sw[k] = expf(-(d0 * d0 + d1 * d1 + d2 * d2) * 0.5f);
    }
    __syncthreads();

    if (k == 0) {
        float aw[MM];
        for (int j = 0; j < MM; ++j) aw[j] = 0.0f;
        for (int h = 0; h < 4; ++h) {               // softmax over m, per head
            float mx = s_attn[0][h];
            for (int j = 1; j < MM; ++j) mx = fmaxf(mx, s_attn[j][h]);
            float e[MM]; float sum = 0.0f;
            for (int j = 0; j < MM; ++j) { e[j] = expf(s_attn[j][h] - mx); sum += e[j]; }
            for (int j = 0; j < MM; ++j) aw[j] += e[j] / sum;
        }
        float swsum = 0.0f;
        for (int j = 0; j < MM; ++j) swsum += s_sw[j];
        float wj[MM]; float wsum = 0.0f;
        for (int j = 0; j < MM; ++j) {
            wj[j] = (aw[j] * 0.25f) * (s_sw[j] / swsum);
            wsum += wj[j];
        }
        s_wm = wj[m] / wsum;
    }

    // ys row for this m — EXACT fp32 op sequence of the reference:
    // ys[j] = fl( fl(l01[j]*ly) * fl(75/ly) ),  l01[j] = fl(j * fl(1/255))
    {
        float ly  = params[m * 3 + 0];
        float inv = 75.0f / ly;                    // IEEE divide (no fast-math)
        float l01 = (float)k * (1.0f / 255.0f);
        s_ys[k] = (l01 * ly) * inv;
    }
    __syncthreads();

    float w  = s_wm;
    float yq = (float)k * (75.0f / 255.0f);        // rounds to exactly 75.0 at k=255
    // upper_bound: largest j with ys[j] <= yq  (== searchsorted 'right' - 1)
    int l = 0, r = NYY;
    while (l < r) { int mid = (l + r) >> 1; if (s_ys[mid] <= yq) l = mid + 1; else r = mid; }
    int iy = l - 1;
    iy = iy < 0 ? 0 : (iy > NYY - 2 ? NYY - 2 : iy);
    float ty  = (yq - s_ys[iy]) / (s_ys[iy + 1] - s_ys[iy]);
    bool  inb = (yq >= s_ys[0]) && (yq <= s_ys[NYY - 1]);   // the k=255 knife edge
    g_iy[m * NOUTT + k] = iy;
    g_w0[m * NOUTT + k] = inb ? w * (1.0f - ty) : 0.0f;
    g_w1[m * NOUTT + k] = inb ? w * ty : 0.0f;
}

// grid: (NOUTT/IPB, NTT), block 256 (4 waves).
// Stage IPB output-rows' worth of source rows (IPB*24 rows x 1KB) into LDS
// via global_load_lds (16B/lane, zero dest VGPRs -> all DMAs in flight),
// then y-lerp from LDS. x-interp is identity (xq == xs bitwise).
__global__ __launch_bounds__(256) void ai_resample_kernel(
    const float* __restrict__ c1, const float* __restrict__ c2,
    float* __restrict__ out)
{
    __shared__ float s_rows[IPB * 24 * NYY];   // 48 KB -> 3 blocks/CU

    const int tid  = threadIdx.x;
    const int lane = tid & 63;
    const int wv   = tid >> 6;
    const int t    = blockIdx.y;
    const int i0   = blockIdx.x * IPB;
    int tsrc = (t * TSOL) / (NTT - 1);         // floor(t*64/49), fp-robust
    if (tsrc > TSOL - 1) tsrc = TSOL - 1;

    // Per-k tables into regs first — these VMEM loads overlap the LDS DMA.
    int   iy[MM]; float w0[MM], w1[MM];
#pragma unroll
    for (int m = 0; m < MM; ++m) {
        iy[m] = g_iy[m * NOUTT + tid];
        w0[m] = g_w0[m * NOUTT + tid];
        w1[m] = g_w1[m * NOUTT + tid];
    }

    // Each (wave, s) DMAs one full 1KB source row: global base+lane*16 ->
    // LDS row_base+lane*16 (the required wave-uniform-base pattern).
#pragma unroll
    for (int s = 0; s < IPB * 24 / 4; ++s) {
        int rs  = s * 4 + wv;                  // 0 .. IPB*24-1
        int r   = rs / 24;                     // which output row of the block
        int row = rs % 24;                     // 0..11 -> c1, 12..23 -> c2
        int ch  = row / 12;
        int m   = row % 12;
        const float* src = ch ? c2 : c1;
        size_t gbase = ((size_t)(m * TSOL + tsrc) * NXX + (size_t)(i0 + r)) * NYY;
        const float* gp = src + gbase + (size_t)lane * 4;
        float* lp = &s_rows[rs * NYY];         // wave-uniform LDS base
        __builtin_amdgcn_global_load_lds(
            (const __attribute__((address_space(1))) void*)gp,
            (__attribute__((address_space(3))) void*)lp,
            16, 0, 0);
    }
    __syncthreads();

#pragma unroll
    for (int r = 0; r < IPB; ++r) {
        const float* rowset = &s_rows[r * 24 * NYY];
        float acc1 = 0.0f, acc2 = 0.0f;
#pragma unroll
        for (int m = 0; m < MM; ++m) {
            const float* r1 = rowset + m * NYY;
            const float* r2 = rowset + (12 + m) * NYY;
            int j = iy[m];
            float a0 = r1[j], a1 = r1[j + 1];
            float b0 = r2[j], b1 = r2[j + 1];
            acc1 += w0[m] * a0 + w1[m] * a1;
            acc2 += w0[m] * b0 + w1[m] * b1;
        }
        int i = i0 + r;
        float o1 = (tid == 0)         ? 0.001f  : acc1;  // c1[:,:,0]  = C_CU_TARGET
        float o2 = (tid == NOUTT - 1) ? 0.0001f : acc2;  // c2[:,:,-1] = C_NI_TARGET
        out[((size_t)t * NOUTT + (size_t)i) * NOUTT + (size_t)tid] = o1;
        out[((size_t)(NTT + t) * NOUTT + (size_t)i) * NOUTT + (size_t)tid] = o2;
    }
}

extern "C" void kernel_launch(void* const* d_in, const int* in_sizes, int n_in,
                              void* d_out, int out_size, void* d_ws, size_t ws_size,
                              hipStream_t stream) {
    const float* params = (const float*)d_in[0];
    const float* c1     = (const float*)d_in[1];
    const float* c2     = (const float*)d_in[2];
    const float* Wq     = (const float*)d_in[3];
    const float* bq     = (const float*)d_in[4];
    const float* Wk     = (const float*)d_in[5];
    const float* bk     = (const float*)d_in[6];
    float* out = (float*)d_out;

    ai_setup_kernel<<<dim3(MM), dim3(256), 0, stream>>>(params, Wq, bq, Wk, bk);
    ai_resample_kernel<<<dim3(NOUTT / IPB, NTT), dim3(256), 0, stream>>>(c1, c2, out);
}